// Round 2
// baseline (157.248 us; speedup 1.0000x reference)
//
#include <hip/hip_runtime.h>
#include <hip/hip_bf16.h>

typedef unsigned short u16;
typedef __bf16 bf16x8 __attribute__((ext_vector_type(8)));
typedef float f32x4 __attribute__((ext_vector_type(4)));
typedef u16 u16x4 __attribute__((ext_vector_type(4)));

#define B_ 2
#define L_ 2048
#define D_ 128
#define KLAY 3
#define NR 16
#define NATOM 118
#define NJC 4
#define BLD (B_ * L_ * D_)

static __device__ __forceinline__ u16 f2bf(float f) {
    union { float f; unsigned u; } v; v.f = f;
    unsigned r = v.u + 0x7FFFu + ((v.u >> 16) & 1u);
    return (u16)(r >> 16);
}
static __device__ __forceinline__ bf16x8 ld_bf8(const u16* p) {
    return *(const bf16x8*)p;
}

// ---------------- prep: transpose weights to bf16 [n][k] layouts ----------------
__global__ __launch_bounds__(256) void prep_kernel(
    const float* atom_emb, const float* out_w, const float* self_w,
    const float* msg_w, const float* upd_w,
    u16* atom16, u16* outwT, u16* selfT, u16* msgT, u16* updT) {
    const int T0 = NATOM * D_;
    const int T1 = D_ * 2 * D_;
    const int T2 = KLAY * D_ * D_;
    const int T3 = KLAY * D_ * D_;
    const int T4 = KLAY * D_ * 2 * D_;
    int total = T0 + T1 + T2 + T3 + T4;
    for (int t = blockIdx.x * blockDim.x + threadIdx.x; t < total;
         t += gridDim.x * blockDim.x) {
        int u = t;
        if (u < T0) { atom16[u] = f2bf(atom_emb[u]); continue; }
        u -= T0;
        if (u < T1) {
            int n = u / (2 * D_), k = u % (2 * D_);
            outwT[u] = f2bf(out_w[k * D_ + n]);
            continue;
        }
        u -= T1;
        if (u < T2) {
            int kk = u / (D_ * D_), v = u % (D_ * D_);
            int n = v / D_, k = v % D_;
            selfT[u] = f2bf(self_w[kk * D_ * D_ + k * D_ + n]);
            continue;
        }
        u -= T2;
        if (u < T3) {
            int kk = u / (D_ * D_), v = u % (D_ * D_);
            int n = v / D_, k = v % D_;
            msgT[u] = f2bf(msg_w[kk * D_ * D_ + k * D_ + n]);
            continue;
        }
        u -= T3;
        {
            int kk = u / (D_ * 2 * D_), v = u % (D_ * 2 * D_);
            int n = v / (2 * D_), k = v % (2 * D_);
            updT[u] = f2bf(upd_w[kk * 2 * D_ * D_ + k * D_ + n]);
        }
    }
}

// ---------------- pairwise: W16 = bf16(exp(-dist)), rbf_local mean ----------------
__global__ __launch_bounds__(256) void pairwise_kernel(
    const float* coords, const float* gamma_p, const float* centers,
    u16* W16, float* rbf_loc) {
    int bi = blockIdx.x;  // b*L + i
    int b = bi >> 11;
    int tid = threadIdx.x;
    float gamma = gamma_p[0];
    __shared__ float cen[NR];
    if (tid < NR) cen[tid] = centers[tid];
    float cx = coords[bi * 3 + 0];
    float cy = coords[bi * 3 + 1];
    float cz = coords[bi * 3 + 2];
    float acc[NR];
#pragma unroll
    for (int r = 0; r < NR; r++) acc[r] = 0.f;
    __syncthreads();
    const float* cb = coords + (size_t)b * L_ * 3;
    u16* wrow = W16 + (size_t)bi * L_;
    for (int jj = 0; jj < L_; jj += 256) {
        int j = jj + tid;
        float dx = cx - cb[j * 3 + 0];
        float dy = cy - cb[j * 3 + 1];
        float dz = cz - cb[j * 3 + 2];
        float sq = dx * dx + dy * dy + dz * dz;
        float d = sq > 0.f ? sqrtf(sq) : 0.f;
        wrow[j] = f2bf(__expf(-d));
#pragma unroll
        for (int r = 0; r < NR; r++) {
            float t = d - cen[r];
            acc[r] += __expf(-gamma * t * t);
        }
    }
    __shared__ float red[256][NR + 1];
#pragma unroll
    for (int r = 0; r < NR; r++) red[tid][r] = acc[r];
    __syncthreads();
    for (int s = 128; s > 0; s >>= 1) {
        if (tid < s) {
#pragma unroll
            for (int r = 0; r < NR; r++) red[tid][r] += red[tid + s][r];
        }
        __syncthreads();
    }
    if (tid < NR) rbf_loc[(size_t)bi * NR + tid] = red[0][tid] * (1.0f / L_);
}

// ---------------- encoder + first-layer S/X (all row-local, fused) ----------------
__global__ __launch_bounds__(256) void enc_sx_kernel(
    const int* Z, const float* rbf_w, const float* rbf_b, const float* out_b,
    const float* rbf_loc, const u16* atom16, const u16* outwT,
    const u16* selfT0, const u16* msgT0, const float* self_b0, const float* msg_b0,
    u16* S16, u16* XT16) {
    int gi0 = blockIdx.x * 16;
    int b = gi0 >> 11;
    int il0 = gi0 & (L_ - 1);
    int tid = threadIdx.x;
    __shared__ __align__(16) u16 hgeo[16][136];
    __shared__ __align__(16) u16 h_lds[16][136];
    for (int e = tid; e < 16 * D_; e += 256) {
        int row = e >> 7, d = e & 127;
        int gi = gi0 + row;
        float s = rbf_b[d];
#pragma unroll
        for (int r = 0; r < NR; r++)
            s += rbf_loc[(size_t)gi * NR + r] * rbf_w[r * D_ + d];
        hgeo[row][d] = f2bf(s);
    }
    __syncthreads();
    int w = tid >> 6, lane = tid & 63;
    int rowf = lane & 15, kg = lane >> 4;
    f32x4 z = {0.f, 0.f, 0.f, 0.f};
    f32x4 acc[2] = {z, z};
    int za = Z[gi0 + rowf];
    for (int ks = 0; ks < 8; ks++) {
        int k0 = ks * 32 + kg * 8;
        bf16x8 a;
        if (k0 < 128) a = ld_bf8(atom16 + za * D_ + k0);
        else a = ld_bf8(&hgeo[rowf][k0 - 128]);
#pragma unroll
        for (int q = 0; q < 2; q++) {
            int cl = (w * 2 + q) * 16 + rowf;
            bf16x8 bb = ld_bf8(outwT + cl * (2 * D_) + k0);
            acc[q] = __builtin_amdgcn_mfma_f32_16x16x32_bf16(a, bb, acc[q], 0, 0, 0);
        }
    }
#pragma unroll
    for (int q = 0; q < 2; q++) {
        int cl = (w * 2 + q) * 16 + rowf;
        float bias = out_b[cl];
#pragma unroll
        for (int r = 0; r < 4; r++) h_lds[kg * 4 + r][cl] = f2bf(acc[q][r] + bias);
    }
    __syncthreads();
    // S0 = h@self_w0+b (row-major), XT0 = (h@msg_w0+b)^T
    f32x4 acc3[4] = {z, z, z, z};
    for (int ks = 0; ks < 4; ks++) {
        int k0 = ks * 32 + kg * 8;
        bf16x8 a = ld_bf8(&h_lds[rowf][k0]);
#pragma unroll
        for (int q = 0; q < 4; q++) {
            int nb = w * 4 + q;
            const u16* wp = (nb < 8) ? (selfT0 + (nb * 16 + rowf) * D_ + k0)
                                     : (msgT0 + ((nb - 8) * 16 + rowf) * D_ + k0);
            acc3[q] = __builtin_amdgcn_mfma_f32_16x16x32_bf16(a, ld_bf8(wp), acc3[q], 0, 0, 0);
        }
    }
#pragma unroll
    for (int q = 0; q < 4; q++) {
        int nb = w * 4 + q;
        if (nb < 8) {
            int cl = nb * 16 + rowf;
            float bias = self_b0[cl];
#pragma unroll
            for (int r = 0; r < 4; r++)
                S16[(size_t)(gi0 + kg * 4 + r) * D_ + cl] = f2bf(acc3[q][r] + bias);
        } else {
            int cl = (nb - 8) * 16 + rowf;
            float bias = msg_b0[cl];
            u16x4 pk;
#pragma unroll
            for (int r = 0; r < 4; r++) pk[r] = f2bf(acc3[q][r] + bias);
            *(u16x4*)(XT16 + ((size_t)(b * D_ + cl)) * L_ + il0 + kg * 4) = pk;
        }
    }
}

// ---------------- mpA: partial msg over j-chunk; col-split across waves, no LDS ----------------
__global__ __launch_bounds__(256, 4) void mpA_kernel(
    const u16* W16, const u16* XT16, float* pbuf) {
    int bid = blockIdx.x;
    int rt = bid & 255;   // row tile
    int jc = bid >> 8;    // j chunk 0..3
    int gi0 = rt * 16;
    int b = gi0 >> 11;
    int il0 = gi0 & (L_ - 1);
    int tid = threadIdx.x;
    int w = tid >> 6, lane = tid & 63;
    int rowf = lane & 15, kg = lane >> 4;
    int j0 = jc * 512;
    const u16* wbase = W16 + ((size_t)(b * L_ + il0 + rowf)) * L_ + j0 + kg * 8;
    const u16* xbase = XT16 + (size_t)b * D_ * L_ + j0 + kg * 8;
    f32x4 z = {0.f, 0.f, 0.f, 0.f};
    f32x4 acc[2] = {z, z};
    for (int s = 0; s < 16; s++) {
        int j8 = s * 32;
        bf16x8 a = ld_bf8(wbase + j8);
#pragma unroll
        for (int q = 0; q < 2; q++) {
            int cl = (w * 2 + q) * 16 + rowf;
            bf16x8 bb = ld_bf8(xbase + (size_t)cl * L_ + j8);
            acc[q] = __builtin_amdgcn_mfma_f32_16x16x32_bf16(a, bb, acc[q], 0, 0, 0);
        }
    }
    float* pb = pbuf + (size_t)jc * BLD + (size_t)gi0 * D_;
#pragma unroll
    for (int q = 0; q < 2; q++) {
        int cl = (w * 2 + q) * 16 + rowf;
#pragma unroll
        for (int r = 0; r < 4; r++) pb[(kg * 4 + r) * D_ + cl] = acc[q][r];
    }
}

// ---------------- mpB: sum partials, h' = S@U_top + msg@U_bot + b; fused next S/X ----------------
__global__ __launch_bounds__(256) void mpB_kernel(
    const float* pbuf, const u16* S16in, const u16* updT_k, const float* upd_b_k,
    const u16* selfTn, const u16* msgTn, const float* self_bn, const float* msg_bn,
    u16* S16o, u16* XT16, float* out_f32, int last) {
    int gi0 = blockIdx.x * 16;
    int b = gi0 >> 11;
    int il0 = gi0 & (L_ - 1);
    int tid = threadIdx.x;
    int w = tid >> 6, lane = tid & 63;
    int rowf = lane & 15, kg = lane >> 4;
    __shared__ __align__(16) u16 msg_lds[16][136];
    __shared__ __align__(16) u16 h_lds[16][136];
    for (int e = tid; e < 16 * D_; e += 256) {
        int row = e >> 7, col = e & 127;
        size_t off = (size_t)(gi0 + row) * D_ + col;
        float m = pbuf[off] + pbuf[off + BLD] + pbuf[off + 2 * (size_t)BLD] +
                  pbuf[off + 3 * (size_t)BLD];
        msg_lds[row][col] = f2bf(m);
    }
    __syncthreads();
    f32x4 z = {0.f, 0.f, 0.f, 0.f};
    f32x4 acc2[2] = {z, z};
    for (int ks = 0; ks < 4; ks++) {
        int k0 = ks * 32 + kg * 8;
        bf16x8 a_s = ld_bf8(S16in + (size_t)(gi0 + rowf) * D_ + k0);
        bf16x8 a_m = ld_bf8(&msg_lds[rowf][k0]);
#pragma unroll
        for (int q = 0; q < 2; q++) {
            int cl = (w * 2 + q) * 16 + rowf;
            bf16x8 b_s = ld_bf8(updT_k + cl * (2 * D_) + k0);
            bf16x8 b_m = ld_bf8(updT_k + cl * (2 * D_) + 128 + k0);
            acc2[q] = __builtin_amdgcn_mfma_f32_16x16x32_bf16(a_s, b_s, acc2[q], 0, 0, 0);
            acc2[q] = __builtin_amdgcn_mfma_f32_16x16x32_bf16(a_m, b_m, acc2[q], 0, 0, 0);
        }
    }
    if (last) {
#pragma unroll
        for (int q = 0; q < 2; q++) {
            int cl = (w * 2 + q) * 16 + rowf;
            float bias = upd_b_k[cl];
#pragma unroll
            for (int r = 0; r < 4; r++)
                out_f32[(size_t)(gi0 + kg * 4 + r) * D_ + cl] = acc2[q][r] + bias;
        }
        return;
    }
#pragma unroll
    for (int q = 0; q < 2; q++) {
        int cl = (w * 2 + q) * 16 + rowf;
        float bias = upd_b_k[cl];
#pragma unroll
        for (int r = 0; r < 4; r++) h_lds[kg * 4 + r][cl] = f2bf(acc2[q][r] + bias);
    }
    __syncthreads();
    // next-layer S/X (row-local)
    f32x4 acc3[4] = {z, z, z, z};
    for (int ks = 0; ks < 4; ks++) {
        int k0 = ks * 32 + kg * 8;
        bf16x8 a = ld_bf8(&h_lds[rowf][k0]);
#pragma unroll
        for (int q = 0; q < 4; q++) {
            int nb = w * 4 + q;
            const u16* wp = (nb < 8) ? (selfTn + (nb * 16 + rowf) * D_ + k0)
                                     : (msgTn + ((nb - 8) * 16 + rowf) * D_ + k0);
            acc3[q] = __builtin_amdgcn_mfma_f32_16x16x32_bf16(a, ld_bf8(wp), acc3[q], 0, 0, 0);
        }
    }
#pragma unroll
    for (int q = 0; q < 4; q++) {
        int nb = w * 4 + q;
        if (nb < 8) {
            int cl = nb * 16 + rowf;
            float bias = self_bn[cl];
#pragma unroll
            for (int r = 0; r < 4; r++)
                S16o[(size_t)(gi0 + kg * 4 + r) * D_ + cl] = f2bf(acc3[q][r] + bias);
        } else {
            int cl = (nb - 8) * 16 + rowf;
            float bias = msg_bn[cl];
            u16x4 pk;
#pragma unroll
            for (int r = 0; r < 4; r++) pk[r] = f2bf(acc3[q][r] + bias);
            *(u16x4*)(XT16 + ((size_t)(b * D_ + cl)) * L_ + il0 + kg * 4) = pk;
        }
    }
}

extern "C" void kernel_launch(void* const* d_in, const int* in_sizes, int n_in,
                              void* d_out, int out_size, void* d_ws, size_t ws_size,
                              hipStream_t stream) {
    const float* coords = (const float*)d_in[0];
    const int* Z = (const int*)d_in[1];
    const float* atom_emb = (const float*)d_in[2];
    const float* gamma = (const float*)d_in[3];
    const float* centers = (const float*)d_in[4];
    const float* rbf_w = (const float*)d_in[5];
    const float* rbf_b = (const float*)d_in[6];
    const float* out_w = (const float*)d_in[7];
    const float* out_b = (const float*)d_in[8];
    const float* self_w = (const float*)d_in[9];
    const float* self_b = (const float*)d_in[10];
    const float* msg_w = (const float*)d_in[11];
    const float* msg_b = (const float*)d_in[12];
    const float* upd_w = (const float*)d_in[13];
    const float* upd_b = (const float*)d_in[14];
    float* out = (float*)d_out;

    char* ws = (char*)d_ws;
    u16* W16 = (u16*)(ws + 0);               // 16,777,216
    u16* S16 = (u16*)(ws + 16777216);        // 1,048,576
    u16* XT16 = (u16*)(ws + 17825792);       // 1,048,576
    float* pbuf = (float*)(ws + 18874368);   // 8,388,608 (4 chunks fp32)
    float* rbfl = (float*)(ws + 27262976);   // 262,144
    u16* atom16 = (u16*)(ws + 27525120);     // 32,768
    u16* outwT = (u16*)(ws + 27557888);      // 65,536
    u16* selfT = (u16*)(ws + 27623424);      // 98,304
    u16* msgT = (u16*)(ws + 27721728);       // 98,304
    u16* updT = (u16*)(ws + 27820032);       // 196,608

    prep_kernel<<<64, 256, 0, stream>>>(atom_emb, out_w, self_w, msg_w, upd_w,
                                        atom16, outwT, selfT, msgT, updT);
    pairwise_kernel<<<B_ * L_, 256, 0, stream>>>(coords, gamma, centers, W16, rbfl);
    enc_sx_kernel<<<(B_ * L_) / 16, 256, 0, stream>>>(
        Z, rbf_w, rbf_b, out_b, rbfl, atom16, outwT,
        selfT, msgT, self_b, msg_b, S16, XT16);
    for (int k = 0; k < KLAY; k++) {
        int last = (k == KLAY - 1);
        const u16* selfTn = last ? selfT : selfT + (k + 1) * D_ * D_;
        const u16* msgTn = last ? msgT : msgT + (k + 1) * D_ * D_;
        const float* self_bn = last ? self_b : self_b + (k + 1) * D_;
        const float* msg_bn = last ? msg_b : msg_b + (k + 1) * D_;
        mpA_kernel<<<NJC * 256, 256, 0, stream>>>(W16, XT16, pbuf);
        mpB_kernel<<<256, 256, 0, stream>>>(
            pbuf, S16, updT + k * D_ * 2 * D_, upd_b + k * D_,
            selfTn, msgTn, self_bn, msg_bn, S16, XT16, out, last);
    }
}

// Round 3
// 132.654 us; speedup vs baseline: 1.1854x; 1.1854x over previous
//
#include <hip/hip_runtime.h>
#include <hip/hip_bf16.h>

typedef unsigned short u16;
typedef __bf16 bf16x8 __attribute__((ext_vector_type(8)));
typedef float f32x4 __attribute__((ext_vector_type(4)));
typedef u16 u16x4 __attribute__((ext_vector_type(4)));

#define B_ 2
#define L_ 2048
#define D_ 128
#define KLAY 3
#define NR 16
#define NATOM 118
#define JW 256  // j-range per wave in mp_fused (8 waves x 256 = 2048)

static __device__ __forceinline__ u16 f2bf(float f) {
    union { float f; unsigned u; } v; v.f = f;
    unsigned r = v.u + 0x7FFFu + ((v.u >> 16) & 1u);
    return (u16)(r >> 16);
}
static __device__ __forceinline__ bf16x8 ld_bf8(const u16* p) {
    return *(const bf16x8*)p;
}

// ---------------- prep: transpose weights to bf16 [n][k] layouts ----------------
__global__ __launch_bounds__(256) void prep_kernel(
    const float* atom_emb, const float* out_w, const float* self_w,
    const float* msg_w, const float* upd_w,
    u16* atom16, u16* outwT, u16* selfT, u16* msgT, u16* updT) {
    const int T0 = NATOM * D_;
    const int T1 = D_ * 2 * D_;
    const int T2 = KLAY * D_ * D_;
    const int T3 = KLAY * D_ * D_;
    const int T4 = KLAY * D_ * 2 * D_;
    int total = T0 + T1 + T2 + T3 + T4;
    for (int t = blockIdx.x * blockDim.x + threadIdx.x; t < total;
         t += gridDim.x * blockDim.x) {
        int u = t;
        if (u < T0) { atom16[u] = f2bf(atom_emb[u]); continue; }
        u -= T0;
        if (u < T1) {
            int n = u / (2 * D_), k = u % (2 * D_);
            outwT[u] = f2bf(out_w[k * D_ + n]);
            continue;
        }
        u -= T1;
        if (u < T2) {
            int kk = u / (D_ * D_), v = u % (D_ * D_);
            int n = v / D_, k = v % D_;
            selfT[u] = f2bf(self_w[kk * D_ * D_ + k * D_ + n]);
            continue;
        }
        u -= T2;
        if (u < T3) {
            int kk = u / (D_ * D_), v = u % (D_ * D_);
            int n = v / D_, k = v % D_;
            msgT[u] = f2bf(msg_w[kk * D_ * D_ + k * D_ + n]);
            continue;
        }
        u -= T3;
        {
            int kk = u / (D_ * 2 * D_), v = u % (D_ * 2 * D_);
            int n = v / (2 * D_), k = v % (2 * D_);
            updT[u] = f2bf(upd_w[kk * 2 * D_ * D_ + k * D_ + n]);
        }
    }
}

// ---------------- pairwise: W16 = bf16(exp(-dist)), rbf_local mean ----------------
__global__ __launch_bounds__(256) void pairwise_kernel(
    const float* coords, const float* gamma_p, const float* centers,
    u16* W16, float* rbf_loc) {
    int bi = blockIdx.x;  // b*L + i
    int b = bi >> 11;
    int tid = threadIdx.x;
    float gamma = gamma_p[0];
    __shared__ float cen[NR];
    if (tid < NR) cen[tid] = centers[tid];
    float cx = coords[bi * 3 + 0];
    float cy = coords[bi * 3 + 1];
    float cz = coords[bi * 3 + 2];
    float acc[NR];
#pragma unroll
    for (int r = 0; r < NR; r++) acc[r] = 0.f;
    __syncthreads();
    const float* cb = coords + (size_t)b * L_ * 3;
    u16* wrow = W16 + (size_t)bi * L_;
    for (int jj = 0; jj < L_; jj += 256) {
        int j = jj + tid;
        float dx = cx - cb[j * 3 + 0];
        float dy = cy - cb[j * 3 + 1];
        float dz = cz - cb[j * 3 + 2];
        float sq = dx * dx + dy * dy + dz * dz;
        float d = sq > 0.f ? sqrtf(sq) : 0.f;
        wrow[j] = f2bf(__expf(-d));
#pragma unroll
        for (int r = 0; r < NR; r++) {
            float t = d - cen[r];
            acc[r] += __expf(-gamma * t * t);
        }
    }
    __shared__ float red[256][NR + 1];
#pragma unroll
    for (int r = 0; r < NR; r++) red[tid][r] = acc[r];
    __syncthreads();
    for (int s = 128; s > 0; s >>= 1) {
        if (tid < s) {
#pragma unroll
            for (int r = 0; r < NR; r++) red[tid][r] += red[tid + s][r];
        }
        __syncthreads();
    }
    if (tid < NR) rbf_loc[(size_t)bi * NR + tid] = red[0][tid] * (1.0f / L_);
}

// ---------------- encoder + first-layer S/X (all row-local, fused) ----------------
__global__ __launch_bounds__(256) void enc_sx_kernel(
    const int* Z, const float* rbf_w, const float* rbf_b, const float* out_b,
    const float* rbf_loc, const u16* atom16, const u16* outwT,
    const u16* selfT0, const u16* msgT0, const float* self_b0, const float* msg_b0,
    u16* S16, u16* XT16) {
    int gi0 = blockIdx.x * 16;
    int b = gi0 >> 11;
    int il0 = gi0 & (L_ - 1);
    int tid = threadIdx.x;
    __shared__ __align__(16) u16 hgeo[16][136];
    __shared__ __align__(16) u16 h_lds[16][136];
    for (int e = tid; e < 16 * D_; e += 256) {
        int row = e >> 7, d = e & 127;
        int gi = gi0 + row;
        float s = rbf_b[d];
#pragma unroll
        for (int r = 0; r < NR; r++)
            s += rbf_loc[(size_t)gi * NR + r] * rbf_w[r * D_ + d];
        hgeo[row][d] = f2bf(s);
    }
    __syncthreads();
    int w = tid >> 6, lane = tid & 63;
    int rowf = lane & 15, kg = lane >> 4;
    f32x4 z = {0.f, 0.f, 0.f, 0.f};
    f32x4 acc[2] = {z, z};
    int za = Z[gi0 + rowf];
    for (int ks = 0; ks < 8; ks++) {
        int k0 = ks * 32 + kg * 8;
        bf16x8 a;
        if (k0 < 128) a = ld_bf8(atom16 + za * D_ + k0);
        else a = ld_bf8(&hgeo[rowf][k0 - 128]);
#pragma unroll
        for (int q = 0; q < 2; q++) {
            int cl = (w * 2 + q) * 16 + rowf;
            bf16x8 bb = ld_bf8(outwT + cl * (2 * D_) + k0);
            acc[q] = __builtin_amdgcn_mfma_f32_16x16x32_bf16(a, bb, acc[q], 0, 0, 0);
        }
    }
#pragma unroll
    for (int q = 0; q < 2; q++) {
        int cl = (w * 2 + q) * 16 + rowf;
        float bias = out_b[cl];
#pragma unroll
        for (int r = 0; r < 4; r++) h_lds[kg * 4 + r][cl] = f2bf(acc[q][r] + bias);
    }
    __syncthreads();
    f32x4 acc3[4] = {z, z, z, z};
    for (int ks = 0; ks < 4; ks++) {
        int k0 = ks * 32 + kg * 8;
        bf16x8 a = ld_bf8(&h_lds[rowf][k0]);
#pragma unroll
        for (int q = 0; q < 4; q++) {
            int nb = w * 4 + q;
            const u16* wp = (nb < 8) ? (selfT0 + (nb * 16 + rowf) * D_ + k0)
                                     : (msgT0 + ((nb - 8) * 16 + rowf) * D_ + k0);
            acc3[q] = __builtin_amdgcn_mfma_f32_16x16x32_bf16(a, ld_bf8(wp), acc3[q], 0, 0, 0);
        }
    }
#pragma unroll
    for (int q = 0; q < 4; q++) {
        int nb = w * 4 + q;
        if (nb < 8) {
            int cl = nb * 16 + rowf;
            float bias = self_b0[cl];
#pragma unroll
            for (int r = 0; r < 4; r++)
                S16[(size_t)(gi0 + kg * 4 + r) * D_ + cl] = f2bf(acc3[q][r] + bias);
        } else {
            int cl = (nb - 8) * 16 + rowf;
            float bias = msg_b0[cl];
            u16x4 pk;
#pragma unroll
            for (int r = 0; r < 4; r++) pk[r] = f2bf(acc3[q][r] + bias);
            *(u16x4*)(XT16 + ((size_t)(b * D_ + cl)) * L_ + il0 + kg * 4) = pk;
        }
    }
}

// ---------------- mp_fused: msg GEMM (8-wave j-split, LDS tree reduce) +
//                  epilogue h' = S@U_top + msg@U_bot + b + next-layer S/X ----------------
__global__ __launch_bounds__(512, 4) void mp_fused_kernel(
    const u16* W16, const u16* XT_in, const u16* S_in,
    const u16* updT_k, const float* upd_b_k,
    const u16* selfTn, const u16* msgTn, const float* self_bn, const float* msg_bn,
    u16* S_out, u16* XT_out, float* out_f32, int last) {
    int gi0 = blockIdx.x * 16;
    int b = gi0 >> 11;
    int il0 = gi0 & (L_ - 1);
    int tid = threadIdx.x;
    int w = tid >> 6, lane = tid & 63;
    int rowf = lane & 15, kg = lane >> 4;

    __shared__ __align__(16) float red[4][16][128];  // 32 KB
    u16* msg_lds = (u16*)&red[0][0][0];              // [16][136] bf16, aliased
    u16* h_lds = (u16*)&red[1][0][0];                // [16][136] bf16, aliased

    f32x4 z = {0.f, 0.f, 0.f, 0.f};
    f32x4 acc[8] = {z, z, z, z, z, z, z, z};
    const u16* wbase = W16 + ((size_t)(b * L_ + il0 + rowf)) * L_ + w * JW + kg * 8;
    const u16* xbase = XT_in + (size_t)b * D_ * L_ + w * JW + kg * 8;
    for (int s = 0; s < JW / 32; s++) {
        int j8 = s * 32;
        bf16x8 a = ld_bf8(wbase + j8);
#pragma unroll
        for (int n = 0; n < 8; n++) {
            bf16x8 bb = ld_bf8(xbase + (size_t)(n * 16 + rowf) * L_ + j8);
            acc[n] = __builtin_amdgcn_mfma_f32_16x16x32_bf16(a, bb, acc[n], 0, 0, 0);
        }
    }
    // ---- LDS tree reduce across 8 waves (rotated layout: 2-way banks = free) ----
    auto stash = [&](int slot) {
#pragma unroll
        for (int n = 0; n < 8; n++)
#pragma unroll
            for (int r = 0; r < 4; r++) {
                int row = kg * 4 + r, col = n * 16 + rowf;
                red[slot][row][(col + 4 * row) & 127] = acc[n][r];
            }
    };
    auto grab = [&](int slot) {
#pragma unroll
        for (int n = 0; n < 8; n++)
#pragma unroll
            for (int r = 0; r < 4; r++) {
                int row = kg * 4 + r, col = n * 16 + rowf;
                acc[n][r] += red[slot][row][(col + 4 * row) & 127];
            }
    };
    if (w >= 4) stash(w - 4);
    __syncthreads();
    if (w < 4) grab(w);
    if (w == 2 || w == 3) stash(w);
    __syncthreads();
    if (w < 2) grab(w + 2);
    if (w == 1) stash(3);
    __syncthreads();
    if (w == 0) {
        grab(3);
#pragma unroll
        for (int n = 0; n < 8; n++)
#pragma unroll
            for (int r = 0; r < 4; r++)
                msg_lds[(kg * 4 + r) * 136 + n * 16 + rowf] = f2bf(acc[n][r]);
    }
    __syncthreads();
    // ---- epilogue: h' = S@U_top + msg@U_bot + bias (8 waves, 1 col-block each) ----
    f32x4 acc2 = z;
    int cl = w * 16 + rowf;
#pragma unroll
    for (int ks = 0; ks < 8; ks++) {
        int k0 = ks * 32 + kg * 8;
        bf16x8 a_v;
        if (ks < 4) a_v = ld_bf8(S_in + (size_t)(gi0 + rowf) * D_ + k0);
        else a_v = ld_bf8(msg_lds + rowf * 136 + (k0 - 128));
        bf16x8 bb = ld_bf8(updT_k + cl * (2 * D_) + k0);
        acc2 = __builtin_amdgcn_mfma_f32_16x16x32_bf16(a_v, bb, acc2, 0, 0, 0);
    }
    float bias = upd_b_k[cl];
    if (last) {
#pragma unroll
        for (int r = 0; r < 4; r++)
            out_f32[(size_t)(gi0 + kg * 4 + r) * D_ + cl] = acc2[r] + bias;
        return;
    }
#pragma unroll
    for (int r = 0; r < 4; r++)
        h_lds[(kg * 4 + r) * 136 + cl] = f2bf(acc2[r] + bias);
    __syncthreads();
    // ---- next-layer S/X (row-local): wave w does S col-block w and X col-block w ----
    f32x4 acc3[2] = {z, z};
#pragma unroll
    for (int ks = 0; ks < 4; ks++) {
        int k0 = ks * 32 + kg * 8;
        bf16x8 a_v = ld_bf8(h_lds + rowf * 136 + k0);
        acc3[0] = __builtin_amdgcn_mfma_f32_16x16x32_bf16(
            a_v, ld_bf8(selfTn + cl * D_ + k0), acc3[0], 0, 0, 0);
        acc3[1] = __builtin_amdgcn_mfma_f32_16x16x32_bf16(
            a_v, ld_bf8(msgTn + cl * D_ + k0), acc3[1], 0, 0, 0);
    }
    float bs = self_bn[cl], bm = msg_bn[cl];
#pragma unroll
    for (int r = 0; r < 4; r++)
        S_out[(size_t)(gi0 + kg * 4 + r) * D_ + cl] = f2bf(acc3[0][r] + bs);
    u16x4 pk;
#pragma unroll
    for (int r = 0; r < 4; r++) pk[r] = f2bf(acc3[1][r] + bm);
    *(u16x4*)(XT_out + ((size_t)(b * D_ + cl)) * L_ + il0 + kg * 4) = pk;
}

extern "C" void kernel_launch(void* const* d_in, const int* in_sizes, int n_in,
                              void* d_out, int out_size, void* d_ws, size_t ws_size,
                              hipStream_t stream) {
    const float* coords = (const float*)d_in[0];
    const int* Z = (const int*)d_in[1];
    const float* atom_emb = (const float*)d_in[2];
    const float* gamma = (const float*)d_in[3];
    const float* centers = (const float*)d_in[4];
    const float* rbf_w = (const float*)d_in[5];
    const float* rbf_b = (const float*)d_in[6];
    const float* out_w = (const float*)d_in[7];
    const float* out_b = (const float*)d_in[8];
    const float* self_w = (const float*)d_in[9];
    const float* self_b = (const float*)d_in[10];
    const float* msg_w = (const float*)d_in[11];
    const float* msg_b = (const float*)d_in[12];
    const float* upd_w = (const float*)d_in[13];
    const float* upd_b = (const float*)d_in[14];
    float* out = (float*)d_out;

    char* ws = (char*)d_ws;
    u16* W16 = (u16*)(ws + 0);               // 16,777,216
    u16* S_a = (u16*)(ws + 16777216);        // 1,048,576
    u16* S_b = (u16*)(ws + 17825792);        // 1,048,576
    u16* XT_a = (u16*)(ws + 18874368);       // 1,048,576
    u16* XT_b = (u16*)(ws + 19922944);       // 1,048,576
    float* rbfl = (float*)(ws + 20971520);   // 262,144
    u16* atom16 = (u16*)(ws + 21233664);     // 32,768
    u16* outwT = (u16*)(ws + 21266432);      // 65,536
    u16* selfT = (u16*)(ws + 21331968);      // 98,304
    u16* msgT = (u16*)(ws + 21430272);       // 98,304
    u16* updT = (u16*)(ws + 21528576);       // 196,608

    const int DD = D_ * D_;

    prep_kernel<<<64, 256, 0, stream>>>(atom_emb, out_w, self_w, msg_w, upd_w,
                                        atom16, outwT, selfT, msgT, updT);
    pairwise_kernel<<<B_ * L_, 256, 0, stream>>>(coords, gamma, centers, W16, rbfl);
    enc_sx_kernel<<<(B_ * L_) / 16, 256, 0, stream>>>(
        Z, rbf_w, rbf_b, out_b, rbfl, atom16, outwT,
        selfT, msgT, self_b, msg_b, S_a, XT_a);
    // layer 0: a -> b
    mp_fused_kernel<<<256, 512, 0, stream>>>(
        W16, XT_a, S_a, updT + 0 * 2 * DD, upd_b + 0 * D_,
        selfT + 1 * DD, msgT + 1 * DD, self_b + 1 * D_, msg_b + 1 * D_,
        S_b, XT_b, out, 0);
    // layer 1: b -> a
    mp_fused_kernel<<<256, 512, 0, stream>>>(
        W16, XT_b, S_b, updT + 1 * 2 * DD, upd_b + 1 * D_,
        selfT + 2 * DD, msgT + 2 * DD, self_b + 2 * D_, msg_b + 2 * D_,
        S_a, XT_a, out, 0);
    // layer 2 (last): a -> out
    mp_fused_kernel<<<256, 512, 0, stream>>>(
        W16, XT_a, S_a, updT + 2 * 2 * DD, upd_b + 2 * D_,
        selfT, msgT, self_b, msg_b, S_b, XT_b, out, 1);
}